// Round 7
// baseline (709.308 us; speedup 1.0000x reference)
//
#include <hip/hip_runtime.h>

#define MEXP  64
#define HDIM  256
#define INDIM 3
#define ODIM  3
#define BT    128
#define NTILE 64            /* 8192 / BT */
#define SINSC 4.774648292756860f   /* 30 / (2*pi): sin(30 z) = v_sin(z*SINSC) */

typedef __attribute__((ext_vector_type(8))) _Float16 f16x8;
typedef __attribute__((ext_vector_type(4))) _Float16 f16x4;
typedef __attribute__((ext_vector_type(4))) float    f32x4;

// Swizzled LDS byte offset for h[row][colByte]. Row stride 512B (256 ch * 2B).
// XOR of ((row ^ row>>3)&7) into byte bits 4:6 — bijective per row, same on write
// & read; spreads the stride-512B ds_read_b128 B-frag pattern to 2-way (free).
// 8B-aligned and 16B-aligned accesses stay aligned (XOR touches bits >= 4 only).
__device__ __forceinline__ int swz(int row, int byteInRow) {
  return (row * 512 + byteInRow) ^ (((row ^ (row >> 3)) & 7) << 4);
}

// ---------- weight preprocessing: fp32 -> fp16 A-fragment order, SINSC folded ----
// Per (layer,m): chunk c = (ct*8+ks)*64+lane holds (as A-frag for D' = W*H^T)
// w[m][ct*16+(lane&15)][ks*32+(lane>>4)*8 + j] * SINSC, j=0..7.
__global__ void prep_hidden(const float* __restrict__ w1, const float* __restrict__ w2,
                            const float* __restrict__ w3, _Float16* __restrict__ ws) {
  int chunk = blockIdx.x * 256 + threadIdx.x;   // 3*64*8192 chunks of 8 elements
  int lm    = chunk >> 13;                      // layer*64 + m
  int c     = chunk & 8191;
  int layer = lm >> 6, m = lm & 63;
  int lane  = c & 63;
  int ctks  = c >> 6;
  int ct = ctks >> 3, ks = ctks & 7;
  int col = ct * 16 + (lane & 15);
  int k   = ks * 32 + ((lane >> 4) << 3);
  const float* w = (layer == 0) ? w1 : (layer == 1) ? w2 : w3;
  const float* src = w + ((size_t)m * HDIM + col) * HDIM + k;
  f16x8 v;
#pragma unroll
  for (int j = 0; j < 8; ++j) v[j] = (_Float16)(src[j] * SINSC);
  *(f16x8*)(ws + (size_t)chunk * 8) = v;
}

// Final layer wf[m][o][k] -> A-frags with out-rows 3..15 zero-padded (no scale).
__global__ void prep_wf(const float* __restrict__ wf, _Float16* __restrict__ ws) {
  int chunk = blockIdx.x * 256 + threadIdx.x;   // 64*512 chunks
  int m    = chunk >> 9;
  int c    = chunk & 511;                       // ks*64 + lane
  int lane = c & 63;
  int ks   = c >> 6;
  int col  = lane & 15;
  int k    = ks * 32 + ((lane >> 4) << 3);
  f16x8 v;
  if (col < ODIM) {
    const float* src = wf + ((size_t)m * ODIM + col) * HDIM + k;
#pragma unroll
    for (int j = 0; j < 8; ++j) v[j] = (_Float16)src[j];
  } else {
#pragma unroll
    for (int j = 0; j < 8; ++j) v[j] = (_Float16)0.0f;
  }
  *(f16x8*)(ws + (size_t)chunk * 8) = v;
}

// ---------- fused SIREN ----------
// Hidden layer, swapped orientation: D'[ch][row] = W'[ch][k] * H[k][row].
// Each wave owns 32 output channels x all 128 rows. Lane holds 4 consecutive
// channels for one row -> packed ds_write_b64 epilogue.
__device__ __forceinline__ void hidden_layer(char* hb, const _Float16* __restrict__ wl,
                                             const float* __restrict__ bptr,
                                             int wid, int lane, int g) {
  f32x4 acc[8][2] = {};
  const f16x8* wfrag = (const f16x8*)wl;       // chunk (ct*8+ks)*64+lane
  int ct0 = wid * 2, ct1 = ct0 + 1;
  f16x8 A0 = wfrag[(ct0 * 8 + 0) * 64 + lane]; // prefetch ks=0
  f16x8 A1 = wfrag[(ct1 * 8 + 0) * 64 + lane];
#pragma unroll
  for (int ks = 0; ks < 8; ++ks) {
    f16x8 a0 = A0, a1 = A1;
    if (ks < 7) {                              // prefetch next-ks weight frags
      A0 = wfrag[(ct0 * 8 + ks + 1) * 64 + lane];
      A1 = wfrag[(ct1 * 8 + ks + 1) * 64 + lane];
    }
#pragma unroll
    for (int rt = 0; rt < 8; ++rt) {
      f16x8 b = *(const f16x8*)(hb + swz(rt * 16 + (lane & 15), ks * 64 + g * 16));
      acc[rt][0] = __builtin_amdgcn_mfma_f32_16x16x32_f16(a0, b, acc[rt][0], 0, 0, 0);
      acc[rt][1] = __builtin_amdgcn_mfma_f32_16x16x32_f16(a1, b, acc[rt][1], 0, 0, 0);
    }
  }
  __syncthreads();   // all reads of hb complete before overwrite
#pragma unroll
  for (int ct = 0; ct < 2; ++ct) {
    int c0 = wid * 32 + ct * 16 + g * 4;       // 4 consecutive channels per lane
    f32x4 bias = *(const f32x4*)(bptr + c0);
#pragma unroll
    for (int rt = 0; rt < 8; ++rt) {
      f16x4 v;
#pragma unroll
      for (int t = 0; t < 4; ++t)
        v[t] = (_Float16)__builtin_amdgcn_sinf(fmaf(bias[t], SINSC, acc[rt][ct][t]));
      *(f16x4*)(hb + swz(rt * 16 + (lane & 15), c0 * 2)) = v;   // ds_write_b64
    }
  }
  __syncthreads();
}

__global__ __launch_bounds__(512, 4)
void siren_fused(const float* __restrict__ x, const float* __restrict__ w0,
                 const float* __restrict__ b0, const float* __restrict__ b1,
                 const float* __restrict__ b2, const float* __restrict__ b3,
                 const float* __restrict__ bfin, const _Float16* __restrict__ wh,
                 const _Float16* __restrict__ wff, float* __restrict__ out) {
  __shared__ _Float16 hbuf[BT * HDIM];   // 64 KB swizzled fp16 h tile
  char* hb = (char*)hbuf;

  int tid  = threadIdx.x;
  int lane = tid & 63;
  int wid  = tid >> 6;
  int g    = lane >> 4;
  int id   = blockIdx.x;
  // XCD swizzle: XCD = id%8 gets 8 experts -> per-XCD L2 weight set 8*3*128KB = 3MB.
  int m    = ((id & 7) << 3) + ((id >> 3) >> 6);
  int tile = (id >> 3) & (NTILE - 1);

  // ---- layer 0: [BT,3] x w0[m][H,3]^T, fp32 VALU (K=3). 2 threads per column. ----
  {
    int col  = tid & 255;
    int half = tid >> 8;
    const float* wp = w0 + ((size_t)m * HDIM + col) * INDIM;
    float wc0 = wp[0], wc1 = wp[1], wc2 = wp[2];
    float bc  = b0[m * HDIM + col] * SINSC;
    const float* xp = x + ((size_t)tile * BT + half * 64) * INDIM;  // uniform -> s_load
#pragma unroll 4
    for (int r = 0; r < 64; ++r) {
      float z = fmaf(xp[r * 3 + 2], wc2, fmaf(xp[r * 3 + 1], wc1, xp[r * 3] * wc0));
      float h = __builtin_amdgcn_sinf(fmaf(z, SINSC, bc));
      *(_Float16*)(hb + swz(half * 64 + r, col * 2)) = (_Float16)h;
    }
  }
  __syncthreads();

  hidden_layer(hb, wh + ((size_t)0 * MEXP + m) * (HDIM * HDIM), b1 + m * HDIM, wid, lane, g);
  hidden_layer(hb, wh + ((size_t)1 * MEXP + m) * (HDIM * HDIM), b2 + m * HDIM, wid, lane, g);
  hidden_layer(hb, wh + ((size_t)2 * MEXP + m) * (HDIM * HDIM), b3 + m * HDIM, wid, lane, g);

  // ---- final layer: D'[o][row], one 16-row strip per wave; lanes g==0 hold o=t ----
  {
    f32x4 facc = {};
    const f16x8* wfrag = (const f16x8*)(wff + (size_t)m * (16 * HDIM));
#pragma unroll
    for (int ks = 0; ks < 8; ++ks) {
      f16x8 b = *(const f16x8*)(hb + swz(wid * 16 + (lane & 15), ks * 64 + g * 16));
      f16x8 a = wfrag[ks * 64 + lane];
      facc = __builtin_amdgcn_mfma_f32_16x16x32_f16(a, b, facc, 0, 0, 0);
    }
    if (g == 0) {
      size_t r = (size_t)tile * BT + wid * 16 + (lane & 15);
#pragma unroll
      for (int t = 0; t < 3; ++t)
        out[(r * MEXP + m) * ODIM + t] = facc[t] + bfin[m * ODIM + t];
    }
  }
}

extern "C" void kernel_launch(void* const* d_in, const int* in_sizes, int n_in,
                              void* d_out, int out_size, void* d_ws, size_t ws_size,
                              hipStream_t stream) {
  (void)in_sizes; (void)n_in; (void)out_size; (void)ws_size;
  const float* x  = (const float*)d_in[0];
  const float* w0 = (const float*)d_in[1];
  const float* b0 = (const float*)d_in[2];
  const float* w1 = (const float*)d_in[3];
  const float* b1 = (const float*)d_in[4];
  const float* w2 = (const float*)d_in[5];
  const float* b2 = (const float*)d_in[6];
  const float* w3 = (const float*)d_in[7];
  const float* b3 = (const float*)d_in[8];
  const float* wf = (const float*)d_in[9];
  const float* bf = (const float*)d_in[10];

  _Float16* wh  = (_Float16*)d_ws;                       // 3*64*65536 fp16 = 24 MB
  _Float16* wff = wh + (size_t)3 * MEXP * HDIM * HDIM;   // + 64*4096 fp16 = 0.5 MB

  prep_hidden<<<6144, 256, 0, stream>>>(w1, w2, w3, wh);
  prep_wf<<<128, 256, 0, stream>>>(wf, wff);
  siren_fused<<<4096, 512, 0, stream>>>(x, w0, b0, b1, b2, b3, bf, wh, wff, (float*)d_out);
}

// Round 8
// 387.095 us; speedup vs baseline: 1.8324x; 1.8324x over previous
//
#include <hip/hip_runtime.h>

#define MEXP  64
#define HDIM  256
#define INDIM 3
#define ODIM  3
#define BT    128
#define NTILE 64            /* 8192 / BT */
#define SINSC 4.774648292756860f   /* 30 / (2*pi): sin(30 z) = v_sin(z*SINSC) */

typedef __attribute__((ext_vector_type(8))) _Float16 f16x8;
typedef __attribute__((ext_vector_type(4))) _Float16 f16x4;
typedef __attribute__((ext_vector_type(4))) float    f32x4;

// Swizzled LDS byte offset for h[row][colByte]. Row stride 512B (256 ch * 2B).
// XOR of ((row ^ row>>3)&7) into byte bits 4:6 — bijective per row, same on write
// & read; spreads the stride-512B ds_read_b128 B-frag pattern across banks.
// 8B-aligned and 16B-aligned accesses stay aligned (XOR touches bits >= 4 only).
__device__ __forceinline__ int swz(int row, int byteInRow) {
  return (row * 512 + byteInRow) ^ (((row ^ (row >> 3)) & 7) << 4);
}

// ---------- weight preprocessing: fp32 -> fp16 A-fragment order, SINSC folded ----
// Per (layer,m): chunk c = (ct*8+ks)*64+lane holds (as A-frag for D' = W*H^T)
// w[m][ct*16+(lane&15)][ks*32+(lane>>4)*8 + j] * SINSC, j=0..7.
__global__ void prep_hidden(const float* __restrict__ w1, const float* __restrict__ w2,
                            const float* __restrict__ w3, _Float16* __restrict__ ws) {
  int chunk = blockIdx.x * 256 + threadIdx.x;   // 3*64*8192 chunks of 8 elements
  int lm    = chunk >> 13;                      // layer*64 + m
  int c     = chunk & 8191;
  int layer = lm >> 6, m = lm & 63;
  int lane  = c & 63;
  int ctks  = c >> 6;
  int ct = ctks >> 3, ks = ctks & 7;
  int col = ct * 16 + (lane & 15);
  int k   = ks * 32 + ((lane >> 4) << 3);
  const float* w = (layer == 0) ? w1 : (layer == 1) ? w2 : w3;
  const float* src = w + ((size_t)m * HDIM + col) * HDIM + k;
  f16x8 v;
#pragma unroll
  for (int j = 0; j < 8; ++j) v[j] = (_Float16)(src[j] * SINSC);
  *(f16x8*)(ws + (size_t)chunk * 8) = v;
}

// Final layer wf[m][o][k] -> A-frags with out-rows 3..15 zero-padded (no scale).
__global__ void prep_wf(const float* __restrict__ wf, _Float16* __restrict__ ws) {
  int chunk = blockIdx.x * 256 + threadIdx.x;   // 64*512 chunks
  int m    = chunk >> 9;
  int c    = chunk & 511;                       // ks*64 + lane
  int lane = c & 63;
  int ks   = c >> 6;
  int col  = lane & 15;
  int k    = ks * 32 + ((lane >> 4) << 3);
  f16x8 v;
  if (col < ODIM) {
    const float* src = wf + ((size_t)m * ODIM + col) * HDIM + k;
#pragma unroll
    for (int j = 0; j < 8; ++j) v[j] = (_Float16)src[j];
  } else {
#pragma unroll
    for (int j = 0; j < 8; ++j) v[j] = (_Float16)0.0f;
  }
  *(f16x8*)(ws + (size_t)chunk * 8) = v;
}

// ---------- fused SIREN ----------
// Hidden layer, swapped orientation: D'[ch][row] = W'[ch][k] * H[k][row].
// Each wave owns 32 output channels x all 128 rows. Lane holds 4 consecutive
// channels for one row -> packed ds_write_b64 epilogue.
__device__ __forceinline__ void hidden_layer(char* hb, const _Float16* __restrict__ wl,
                                             const float* __restrict__ bptr,
                                             int wid, int lane, int g) {
  f32x4 acc[8][2] = {};
  const f16x8* wfrag = (const f16x8*)wl;       // chunk (ct*8+ks)*64+lane
  int ct0 = wid * 2, ct1 = ct0 + 1;
  f16x8 A0 = wfrag[(ct0 * 8 + 0) * 64 + lane]; // prefetch ks=0
  f16x8 A1 = wfrag[(ct1 * 8 + 0) * 64 + lane];
#pragma unroll
  for (int ks = 0; ks < 8; ++ks) {
    f16x8 a0 = A0, a1 = A1;
    if (ks < 7) {                              // prefetch next-ks weight frags
      A0 = wfrag[(ct0 * 8 + ks + 1) * 64 + lane];
      A1 = wfrag[(ct1 * 8 + ks + 1) * 64 + lane];
    }
#pragma unroll
    for (int rt = 0; rt < 8; ++rt) {
      f16x8 b = *(const f16x8*)(hb + swz(rt * 16 + (lane & 15), ks * 64 + g * 16));
      acc[rt][0] = __builtin_amdgcn_mfma_f32_16x16x32_f16(a0, b, acc[rt][0], 0, 0, 0);
      acc[rt][1] = __builtin_amdgcn_mfma_f32_16x16x32_f16(a1, b, acc[rt][1], 0, 0, 0);
    }
  }
  __syncthreads();   // all reads of hb complete before overwrite
#pragma unroll
  for (int ct = 0; ct < 2; ++ct) {
    int c0 = wid * 32 + ct * 16 + g * 4;       // 4 consecutive channels per lane
    f32x4 bias = *(const f32x4*)(bptr + c0);
#pragma unroll
    for (int rt = 0; rt < 8; ++rt) {
      f16x4 v;
#pragma unroll
      for (int t = 0; t < 4; ++t)
        v[t] = (_Float16)__builtin_amdgcn_sinf(fmaf(bias[t], SINSC, acc[rt][ct][t]));
      *(f16x4*)(hb + swz(rt * 16 + (lane & 15), c0 * 2)) = v;   // ds_write_b64
    }
  }
  __syncthreads();
}

// launch_bounds note: (512,4) made the compiler cap VGPRs at 64 (observed in
// rocprof VGPR_Count) -> acc[8][2] spilled to scratch -> 1.8 GB/dispatch HBM
// traffic. (512,2) -> cap >=128, fits the ~110-reg working set, no spill.
__global__ __launch_bounds__(512, 2)
void siren_fused(const float* __restrict__ x, const float* __restrict__ w0,
                 const float* __restrict__ b0, const float* __restrict__ b1,
                 const float* __restrict__ b2, const float* __restrict__ b3,
                 const float* __restrict__ bfin, const _Float16* __restrict__ wh,
                 const _Float16* __restrict__ wff, float* __restrict__ out) {
  __shared__ _Float16 hbuf[BT * HDIM];   // 64 KB swizzled fp16 h tile
  char* hb = (char*)hbuf;

  int tid  = threadIdx.x;
  int lane = tid & 63;
  int wid  = tid >> 6;
  int g    = lane >> 4;
  int id   = blockIdx.x;
  // XCD swizzle: XCD = id%8 gets 8 experts -> per-XCD L2 weight set 8*3*128KB = 3MB.
  int m    = ((id & 7) << 3) + ((id >> 3) >> 6);
  int tile = (id >> 3) & (NTILE - 1);

  // ---- layer 0: [BT,3] x w0[m][H,3]^T, fp32 VALU (K=3). 2 threads per column. ----
  {
    int col  = tid & 255;
    int half = tid >> 8;
    const float* wp = w0 + ((size_t)m * HDIM + col) * INDIM;
    float wc0 = wp[0], wc1 = wp[1], wc2 = wp[2];
    float bc  = b0[m * HDIM + col] * SINSC;
    const float* xp = x + ((size_t)tile * BT + half * 64) * INDIM;  // uniform -> s_load
#pragma unroll 4
    for (int r = 0; r < 64; ++r) {
      float z = fmaf(xp[r * 3 + 2], wc2, fmaf(xp[r * 3 + 1], wc1, xp[r * 3] * wc0));
      float h = __builtin_amdgcn_sinf(fmaf(z, SINSC, bc));
      *(_Float16*)(hb + swz(half * 64 + r, col * 2)) = (_Float16)h;
    }
  }
  __syncthreads();

  hidden_layer(hb, wh + ((size_t)0 * MEXP + m) * (HDIM * HDIM), b1 + m * HDIM, wid, lane, g);
  hidden_layer(hb, wh + ((size_t)1 * MEXP + m) * (HDIM * HDIM), b2 + m * HDIM, wid, lane, g);
  hidden_layer(hb, wh + ((size_t)2 * MEXP + m) * (HDIM * HDIM), b3 + m * HDIM, wid, lane, g);

  // ---- final layer: D'[o][row], one 16-row strip per wave; lanes g==0 hold o=t ----
  {
    f32x4 facc = {};
    const f16x8* wfrag = (const f16x8*)(wff + (size_t)m * (16 * HDIM));
#pragma unroll
    for (int ks = 0; ks < 8; ++ks) {
      f16x8 b = *(const f16x8*)(hb + swz(wid * 16 + (lane & 15), ks * 64 + g * 16));
      f16x8 a = wfrag[ks * 64 + lane];
      facc = __builtin_amdgcn_mfma_f32_16x16x32_f16(a, b, facc, 0, 0, 0);
    }
    if (g == 0) {
      size_t r = (size_t)tile * BT + wid * 16 + (lane & 15);
#pragma unroll
      for (int t = 0; t < 3; ++t)
        out[(r * MEXP + m) * ODIM + t] = facc[t] + bfin[m * ODIM + t];
    }
  }
}

extern "C" void kernel_launch(void* const* d_in, const int* in_sizes, int n_in,
                              void* d_out, int out_size, void* d_ws, size_t ws_size,
                              hipStream_t stream) {
  (void)in_sizes; (void)n_in; (void)out_size; (void)ws_size;
  const float* x  = (const float*)d_in[0];
  const float* w0 = (const float*)d_in[1];
  const float* b0 = (const float*)d_in[2];
  const float* w1 = (const float*)d_in[3];
  const float* b1 = (const float*)d_in[4];
  const float* w2 = (const float*)d_in[5];
  const float* b2 = (const float*)d_in[6];
  const float* w3 = (const float*)d_in[7];
  const float* b3 = (const float*)d_in[8];
  const float* wf = (const float*)d_in[9];
  const float* bf = (const float*)d_in[10];

  _Float16* wh  = (_Float16*)d_ws;                       // 3*64*65536 fp16 = 24 MB
  _Float16* wff = wh + (size_t)3 * MEXP * HDIM * HDIM;   // + 64*4096 fp16 = 0.5 MB

  prep_hidden<<<6144, 256, 0, stream>>>(w1, w2, w3, wh);
  prep_wf<<<128, 256, 0, stream>>>(wf, wff);
  siren_fused<<<4096, 512, 0, stream>>>(x, w0, b0, b1, b2, b3, bf, wh, wff, (float*)d_out);
}